// Round 5
// baseline (564.056 us; speedup 1.0000x reference)
//
#include <hip/hip_runtime.h>

typedef unsigned short u16;
typedef __attribute__((ext_vector_type(8))) __bf16 bf8_t;
typedef __attribute__((ext_vector_type(4))) float f4_t;

union bf8u { u16 u[8]; bf8_t v; uint4 q; };

// ---------- bf16 helpers ----------
__device__ __forceinline__ float bf2f(u16 v) {
  return __uint_as_float(((unsigned int)v) << 16);
}
__device__ __forceinline__ u16 f2bf(float f) {
  unsigned int u = __float_as_uint(f);
  unsigned int r = u + 0x7FFFu + ((u >> 16) & 1u);  // RNE
  return (u16)(r >> 16);
}
__device__ __forceinline__ float bflo(unsigned int w) { return __uint_as_float(w << 16); }
__device__ __forceinline__ float bfhi(unsigned int w) { return __uint_as_float(w & 0xFFFF0000u); }
__device__ __forceinline__ float ldf1(const void* p, size_t i, int isf32) {
  return isf32 ? ((const float*)p)[i] : bf2f(((const u16*)p)[i]);
}

// ---------- sizes ----------
#define LQ    2500
#define LQP   2560      /* padded token count for Vt */
#define BB    2
#define CC    256
#define NCC   6
#define HFF   64
#define WFF   176
#define DFF   1024
#define MROWS 5000

// ---------- workspace byte offsets (end = 19,987,072 + 2,560,000 < 20.7MB proven) ----------
#define WB_UV   256
#define WB_WQKV 240256
#define WB_WOP  633472
#define WB_WSC  764544
#define WB_WF1  895616
#define WB_WF2  1419904
#define WB_S1   1944192                 /* 2,621,440 each */
#define WB_S2   (WB_S1 + 2621440)
#define WB_S3   (WB_S2 + 2621440)
#define WB_VT   (WB_S3 + 2621440)       /* 512 x 2560 x 2B */
#define WB_H    WB_S2                   /* overlaps S2,S3,VT (dead at FFN time) */
#define WB_Y3   (WB_S2 + 10485760)      /* = 17,427,072 */

// ============================================================
__global__ void detect_k(const u16* __restrict__ rp, int* __restrict__ flag) {
  int bad = 0;
  for (int i = threadIdx.x; i < 7500; i += 64) {
    float v = bf2f(rp[i]);
    if (!(fabsf(v) < 1e6f)) bad = 1;
  }
  int anybad = __any(bad);
  if (threadIdx.x == 0) flag[0] = anybad ? 1 : 0;   // 1 = f32, 0 = bf16
}

// ============================================================
// weight prep: convert / transpose / zero-fill into bf16 ws
// mode 0: direct convert; 1: transpose (src (Kd,Nd) -> dst (Nd,Kd)); 2: zero Vt pad
// ============================================================
struct WDesc {
  const void* src[6];
  u16* dst[6];
  int n[6];
  int mode[6];
  int Kd[6], Nd[6];
};
__global__ __launch_bounds__(256) void cvtw_k(WDesc d, const int* __restrict__ flag) {
  const int df = flag[0];
  const int i = blockIdx.y;
  const int n = d.n[i];
  for (int j = blockIdx.x * 256 + threadIdx.x; j < n; j += gridDim.x * 256) {
    if (d.mode[i] == 2) {
      const int row = j / (LQP - LQ), col = LQ + j % (LQP - LQ);
      d.dst[i][(size_t)row * LQP + col] = 0;
    } else if (d.mode[i] == 1) {
      const int K = d.Kd[i], N = d.Nd[i];
      const int nn = j / K, kk = j - nn * K;
      d.dst[i][j] = f2bf(ldf1(d.src[i], (size_t)kk * N + nn, df));
    } else {
      d.dst[i][j] = f2bf(ldf1(d.src[i], j, df));
    }
  }
}

// ============================================================
// No-LDS MFMA GEMM: wave (64 thr/block) computes 16M x 64N.
// Y = act(X @ W^T + bias) [+res]. W bf16 ws (N,K), k contiguous.
// XRAW: X flagged raw. RES: 0 none, 1 bf16 ws, 2 flagged raw.
// STORE_T: write transposed into Vt[(gn + (gm&1)*256)*LQP + (gm>>1)].
// ============================================================
template<int XRAW, int ACT, int RES, int STORE_T>
__global__ __launch_bounds__(64) void gemm_nl(
    const void* __restrict__ Xv, const u16* __restrict__ W,
    const void* __restrict__ bias, size_t boff,
    const void* __restrict__ resv,
    u16* __restrict__ Y, int M, int N, int K, const int* __restrict__ flag)
{
  const int df = flag[0];
  const int lane = threadIdx.x;
  const int ln15 = lane & 15, l4 = lane >> 4;
  const int m0 = blockIdx.x * 16, n0 = blockIdx.y * 64;
  const int am = min(m0 + ln15, M - 1);   // clamped A row (stores guarded)

  f4_t acc[4];
#pragma unroll
  for (int nt = 0; nt < 4; ++nt) acc[nt] = (f4_t){0.f, 0.f, 0.f, 0.f};

  for (int k0 = 0; k0 < K; k0 += 32) {
    bf8u a;
    if (XRAW && df) {
      const float* p = (const float*)Xv + (size_t)am * K + k0 + l4 * 8;
      float4 r0 = *(const float4*)p, r1 = *(const float4*)(p + 4);
      a.u[0]=f2bf(r0.x); a.u[1]=f2bf(r0.y); a.u[2]=f2bf(r0.z); a.u[3]=f2bf(r0.w);
      a.u[4]=f2bf(r1.x); a.u[5]=f2bf(r1.y); a.u[6]=f2bf(r1.z); a.u[7]=f2bf(r1.w);
    } else {
      a.q = *(const uint4*)((const u16*)Xv + (size_t)am * K + k0 + l4 * 8);
    }
#pragma unroll
    for (int nt = 0; nt < 4; ++nt) {
      bf8u b;
      b.q = *(const uint4*)&W[(size_t)(n0 + nt * 16 + ln15) * K + k0 + l4 * 8];
      acc[nt] = __builtin_amdgcn_mfma_f32_16x16x32_bf16(a.v, b.v, acc[nt], 0, 0, 0);
    }
  }
  // epilogue: D col=lane&15, row=(lane>>4)*4+r
#pragma unroll
  for (int nt = 0; nt < 4; ++nt) {
    const int gn = n0 + nt * 16 + ln15;
    const float bv = ldf1(bias, boff + gn, df);
#pragma unroll
    for (int r = 0; r < 4; ++r) {
      const int gm = m0 + l4 * 4 + r;
      if (gm < M) {
        float x = acc[nt][r] + bv;
        if (ACT) x = 0.5f * x * (1.f + erff(x * 0.70710678118654752f));
        if (RES == 1)      x += bf2f(((const u16*)resv)[(size_t)gm * N + gn]);
        else if (RES == 2) x += ldf1(resv, (size_t)gm * N + gn, df);
        if (STORE_T) Y[(size_t)(gn + (gm & 1) * 256) * LQP + (gm >> 1)] = f2bf(x);
        else         Y[(size_t)gm * N + gn] = f2bf(x);
      }
    }
  }
}

// ============================================================
// Barrier-free MFMA flash attention.
// Block 256 thr = 4 independent waves; wave w owns q-strip bx*64+w*16.
// blockIdx.y = b*8+h. Q/K row-major bf16 ws; V pre-transposed (Vt).
// Softmax in exp2 domain (Q pre-scaled by 1/sqrt(32)*log2(e)).
// ============================================================
__global__ __launch_bounds__(256) void attn_mf(
    const u16* __restrict__ Qw, const u16* __restrict__ Kw,
    const u16* __restrict__ Vt, u16* __restrict__ Ow)
{
  __shared__ __align__(16) u16 sP[4][16 * 72];
  const int t = threadIdx.x;
  const int lane = t & 63, w = t >> 6;
  const int ln15 = lane & 15, l4 = lane >> 4;
  const int q0 = blockIdx.x * 64 + w * 16;
  const int by = blockIdx.y;           // b*8+h
  const int b = by >> 3, h = by & 7;
  u16* myP = &sP[w][0];
  const float SCL2E = 0.25505654481f;  // (1/sqrt(32)) * log2(e)

  // Q A-fragment, pre-scaled (loaded once)
  bf8u aq;
  {
    const size_t qaddr = ((size_t)(q0 + ln15) * BB + b) * CC + h * 32 + l4 * 8;
    bf8u qr; qr.q = *(const uint4*)&Qw[qaddr];
#pragma unroll
    for (int i = 0; i < 8; ++i) aq.u[i] = f2bf(bf2f(qr.u[i]) * SCL2E);
  }

  f4_t oacc[2];
  oacc[0] = (f4_t){0.f,0.f,0.f,0.f};
  oacc[1] = (f4_t){0.f,0.f,0.f,0.f};
  float m_r[4] = {-1e30f, -1e30f, -1e30f, -1e30f};
  float l_r[4] = {0.f, 0.f, 0.f, 0.f};

  for (int kt = 0; kt < 40; ++kt) {
    const int kb = kt * 64;
    // ---- S = Q K^T : K fragments direct from global ----
    f4_t sv[4];
#pragma unroll
    for (int nt = 0; nt < 4; ++nt) {
      bf8u bk;
      bk.q = *(const uint4*)&Kw[((size_t)(kb + nt * 16 + ln15) * BB + b) * CC + h * 32 + l4 * 8];
      f4_t z = (f4_t){0.f,0.f,0.f,0.f};
      sv[nt] = __builtin_amdgcn_mfma_f32_16x16x32_bf16(aq.v, bk.v, z, 0, 0, 0);
    }
    // ---- mask + online softmax (log2 domain) ----
    float p[4][4];
#pragma unroll
    for (int nt = 0; nt < 4; ++nt) {
      const bool ok = (kb + nt * 16 + ln15) < LQ;
#pragma unroll
      for (int r = 0; r < 4; ++r) p[nt][r] = ok ? sv[nt][r] : -1e30f;
    }
#pragma unroll
    for (int r = 0; r < 4; ++r) {
      float mloc = fmaxf(fmaxf(p[0][r], p[1][r]), fmaxf(p[2][r], p[3][r]));
      mloc = fmaxf(mloc, __shfl_xor(mloc, 1));
      mloc = fmaxf(mloc, __shfl_xor(mloc, 2));
      mloc = fmaxf(mloc, __shfl_xor(mloc, 4));
      mloc = fmaxf(mloc, __shfl_xor(mloc, 8));
      const float mn = fmaxf(m_r[r], mloc);
      const float alpha = __builtin_amdgcn_exp2f(m_r[r] - mn);
      m_r[r] = mn;
      float s = 0.f;
#pragma unroll
      for (int nt = 0; nt < 4; ++nt) {
        const float e = __builtin_amdgcn_exp2f(p[nt][r] - mn);
        p[nt][r] = e; s += e;
      }
      s += __shfl_xor(s, 1);
      s += __shfl_xor(s, 2);
      s += __shfl_xor(s, 4);
      s += __shfl_xor(s, 8);
      l_r[r] = l_r[r] * alpha + s;
      oacc[0][r] *= alpha;
      oacc[1][r] *= alpha;
    }
    // ---- P -> wave-private LDS (C-layout -> A-layout), no barrier ----
#pragma unroll
    for (int nt = 0; nt < 4; ++nt)
#pragma unroll
      for (int r = 0; r < 4; ++r)
        myP[(l4 * 4 + r) * 72 + nt * 16 + ln15] = f2bf(p[nt][r]);
    // ---- O += P V : Vt fragments direct from global ----
#pragma unroll
    for (int ks = 0; ks < 2; ++ks) {
      bf8u ap;
      ap.q = *(const uint4*)&myP[ln15 * 72 + ks * 32 + l4 * 8];
#pragma unroll
      for (int nt = 0; nt < 2; ++nt) {
        bf8u bv;
        bv.q = *(const uint4*)&Vt[(size_t)(by * 32 + nt * 16 + ln15) * LQP + kb + ks * 32 + l4 * 8];
        oacc[nt] = __builtin_amdgcn_mfma_f32_16x16x32_bf16(ap.v, bv.v, oacc[nt], 0, 0, 0);
      }
    }
  }
  // ---- epilogue ----
#pragma unroll
  for (int nt = 0; nt < 2; ++nt)
#pragma unroll
    for (int r = 0; r < 4; ++r) {
      const int q = q0 + l4 * 4 + r;
      if (q < LQ) {
        const float val = oacc[nt][r] / l_r[r];
        Ow[((size_t)q * BB + b) * CC + h * 32 + nt * 16 + ln15] = f2bf(val);
      }
    }
}

// ============================================================
// LayerNorm over C=256; one wave per row; 4 rows per block.
// ============================================================
template<int TOOUT>
__global__ __launch_bounds__(256) void ln_k(const u16* __restrict__ X,
    const void* __restrict__ g, const void* __restrict__ be,
    void* __restrict__ Yv, int rows, const int* __restrict__ flag)
{
  const int df = flag[0];
  const int lane = threadIdx.x & 63;
  const int row = blockIdx.x * 4 + (threadIdx.x >> 6);
  if (row >= rows) return;
  uint2 raw = *(const uint2*)(X + (size_t)row * CC + lane * 4);
  float vx = bflo(raw.x), vy = bfhi(raw.x), vz = bflo(raw.y), vw = bfhi(raw.y);
  float s = vx + vy + vz + vw;
#pragma unroll
  for (int o = 1; o < 64; o <<= 1) s += __shfl_xor(s, o);
  const float mean = s * 0.00390625f;
  const float dx = vx - mean, dy = vy - mean, dz = vz - mean, dw = vw - mean;
  float sq = dx*dx + dy*dy + dz*dz + dw*dw;
#pragma unroll
  for (int o = 1; o < 64; o <<= 1) sq += __shfl_xor(sq, o);
  const float rstd = rsqrtf(sq * 0.00390625f + 1e-5f);
  const float g0 = ldf1(g, lane*4+0, df), g1 = ldf1(g, lane*4+1, df);
  const float g2 = ldf1(g, lane*4+2, df), g3 = ldf1(g, lane*4+3, df);
  const float b0 = ldf1(be, lane*4+0, df), b1 = ldf1(be, lane*4+1, df);
  const float b2 = ldf1(be, lane*4+2, df), b3 = ldf1(be, lane*4+3, df);
  const float y0 = dx * rstd * g0 + b0;
  const float y1 = dy * rstd * g1 + b1;
  const float y2 = dz * rstd * g2 + b2;
  const float y3 = dw * rstd * g3 + b3;
  if (TOOUT && df) {
    float* yp = (float*)Yv + (size_t)row * CC + lane * 4;
    *(float4*)yp = make_float4(y0, y1, y2, y3);
  } else {
    u16* yp = (u16*)Yv + (size_t)row * CC + lane * 4;
    unsigned int lo = (unsigned int)f2bf(y0) | ((unsigned int)f2bf(y1) << 16);
    unsigned int hi = (unsigned int)f2bf(y2) | ((unsigned int)f2bf(y3) << 16);
    *(uint2*)yp = make_uint2(lo, hi);
  }
}

// ============================================================
__global__ __launch_bounds__(256) void uv_k(
    const void* __restrict__ refp, const void* __restrict__ intr,
    const void* __restrict__ extr, float* __restrict__ uv,
    const int* __restrict__ flag)
{
  const int df = flag[0];
  const int idx = blockIdx.x * 256 + threadIdx.x;
  if (idx >= BB * NCC * LQ) return;
  const int bc = idx / LQ;
  const int q = idx - bc * LQ;
  float R[3][3], tv[3], Kc[3][3], p[3];
#pragma unroll
  for (int i = 0; i < 3; ++i) {
#pragma unroll
    for (int j = 0; j < 3; ++j) {
      R[i][j] = ldf1(extr, bc*16 + i*4 + j, df);
      Kc[i][j] = ldf1(intr, bc*9 + i*3 + j, df);
    }
    tv[i] = ldf1(extr, bc*16 + i*4 + 3, df);
  }
#pragma unroll
  for (int j = 0; j < 3; ++j) p[j] = ldf1(refp, q*3 + j, df) - tv[j];
  float pc[3];
#pragma unroll
  for (int i = 0; i < 3; ++i) pc[i] = R[0][i]*p[0] + R[1][i]*p[1] + R[2][i]*p[2];
  float im[3];
#pragma unroll
  for (int i = 0; i < 3; ++i) im[i] = Kc[i][0]*pc[0] + Kc[i][1]*pc[1] + Kc[i][2]*pc[2];
  const float z = fmaxf(im[2], 1e-5f);
  uv[(size_t)idx*2 + 0] = im[0] / z - 0.5f;
  uv[(size_t)idx*2 + 1] = im[1] / z - 0.5f;
}

// ============================================================
// Bilinear sampler, mean over cams. Block = (c, b*5+chunk); threads stride q.
// ============================================================
__global__ __launch_bounds__(256) void samp_k(
    const void* __restrict__ feat, const float* __restrict__ uv,
    u16* __restrict__ S, const int* __restrict__ flag)
{
  const int df = flag[0];
  const int c = blockIdx.x;
  const int b = blockIdx.y / 5;
  const int ch = blockIdx.y % 5;
  const int qend = min((ch + 1) * 500, LQ);
  for (int q = ch * 500 + threadIdx.x; q < qend; q += 256) {
    float acc = 0.f;
#pragma unroll
    for (int cam = 0; cam < NCC; ++cam) {
      const int bc = b * NCC + cam;
      const float x = uv[((size_t)bc * LQ + q) * 2 + 0];
      const float y = uv[((size_t)bc * LQ + q) * 2 + 1];
      const float xf = floorf(x), yf = floorf(y);
      const int x0 = (int)xf, y0 = (int)yf;
      const float wx = x - xf, wy = y - yf;
      const size_t base = ((size_t)bc * CC + c) * (HFF * WFF);
      const bool vx0 = (x0 >= 0) & (x0 < WFF);
      const bool vx1 = (x0 + 1 >= 0) & (x0 + 1 < WFF);
      const bool vy0 = (y0 >= 0) & (y0 < HFF);
      const bool vy1 = (y0 + 1 >= 0) & (y0 + 1 < HFF);
      if (vy0) {
        const size_t rb = base + (size_t)y0 * WFF;
        if (vx0) acc += (1.f - wx) * (1.f - wy) * ldf1(feat, rb + x0, df);
        if (vx1) acc += wx * (1.f - wy) * ldf1(feat, rb + x0 + 1, df);
      }
      if (vy1) {
        const size_t rb = base + (size_t)(y0 + 1) * WFF;
        if (vx0) acc += (1.f - wx) * wy * ldf1(feat, rb + x0, df);
        if (vx1) acc += wx * wy * ldf1(feat, rb + x0 + 1, df);
      }
    }
    S[((size_t)q * BB + b) * CC + c] = f2bf(acc * (1.f / 6.f));
  }
}

// ============================================================
extern "C" void kernel_launch(void* const* d_in, const int* in_sizes, int n_in,
                              void* d_out, int out_size, void* d_ws, size_t ws_size,
                              hipStream_t stream) {
  (void)in_sizes; (void)n_in; (void)out_size; (void)ws_size;
  char* base = (char*)d_ws;
  int* flag = (int*)base;
  float* UV = (float*)(base + WB_UV);
  u16* WQKV = (u16*)(base + WB_WQKV);
  u16* WOP  = (u16*)(base + WB_WOP);
  u16* WSC  = (u16*)(base + WB_WSC);
  u16* WF1  = (u16*)(base + WB_WF1);
  u16* WF2  = (u16*)(base + WB_WF2);
  u16* S1 = (u16*)(base + WB_S1);
  u16* S2 = (u16*)(base + WB_S2);
  u16* S3 = (u16*)(base + WB_S3);
  u16* VT = (u16*)(base + WB_VT);
  u16* H  = (u16*)(base + WB_H);
  u16* Y3 = (u16*)(base + WB_Y3);

  detect_k<<<1, 64, 0, stream>>>((const u16*)d_in[3], flag);

  WDesc wd;
  wd.src[0] = d_in[7];  wd.dst[0] = WQKV; wd.n[0] = 196608; wd.mode[0] = 0; wd.Kd[0] = 0;    wd.Nd[0] = 0;
  wd.src[1] = d_in[9];  wd.dst[1] = WOP;  wd.n[1] = 65536;  wd.mode[1] = 0; wd.Kd[1] = 0;    wd.Nd[1] = 0;
  wd.src[2] = d_in[13]; wd.dst[2] = WSC;  wd.n[2] = 65536;  wd.mode[2] = 0; wd.Kd[2] = 0;    wd.Nd[2] = 0;
  wd.src[3] = d_in[17]; wd.dst[3] = WF1;  wd.n[3] = 262144; wd.mode[3] = 1; wd.Kd[3] = 256;  wd.Nd[3] = 1024;
  wd.src[4] = d_in[19]; wd.dst[4] = WF2;  wd.n[4] = 262144; wd.mode[4] = 1; wd.Kd[4] = 1024; wd.Nd[4] = 256;
  wd.src[5] = nullptr;  wd.dst[5] = VT;   wd.n[5] = 512 * (LQP - LQ); wd.mode[5] = 2; wd.Kd[5] = 0; wd.Nd[5] = 0;
  cvtw_k<<<dim3(128, 6), 256, 0, stream>>>(wd, flag);

  uv_k<<<(BB * NCC * LQ + 255) / 256, 256, 0, stream>>>(d_in[3], d_in[4], d_in[5], UV, flag);

  // QKV projections: Q->S1, K->S2, V->VT (transposed store)
  gemm_nl<1,0,0,0><<<dim3(313, 4), 64, 0, stream>>>(d_in[0], WQKV,          d_in[8], 0,   nullptr, S1, MROWS, CC, CC, flag);
  gemm_nl<1,0,0,0><<<dim3(313, 4), 64, 0, stream>>>(d_in[1], WQKV + 65536,  d_in[8], 256, nullptr, S2, MROWS, CC, CC, flag);
  gemm_nl<1,0,0,1><<<dim3(313, 4), 64, 0, stream>>>(d_in[1], WQKV + 131072, d_in[8], 512, nullptr, VT, MROWS, CC, CC, flag);

  attn_mf<<<dim3(40, 16), 256, 0, stream>>>(S1, S2, VT, S3);

  // out-proj (+bevq residual) -> S1, LN1 -> S2
  gemm_nl<0,0,2,0><<<dim3(313, 4), 64, 0, stream>>>(S3, WOP, d_in[10], 0, d_in[0], S1, MROWS, CC, CC, flag);
  ln_k<0><<<1250, 256, 0, stream>>>(S1, d_in[11], d_in[12], S2, MROWS, flag);

  // sampling -> VT slot (dead after attn)
  samp_k<<<dim3(CC, BB * 5), 256, 0, stream>>>(d_in[2], UV, VT, flag);

  // SCA (+S2 residual) -> S3, LN2 -> S1
  gemm_nl<0,0,1,0><<<dim3(313, 4), 64, 0, stream>>>(VT, WSC, d_in[14], 0, S2, S3, MROWS, CC, CC, flag);
  ln_k<0><<<1250, 256, 0, stream>>>(S3, d_in[15], d_in[16], S1, MROWS, flag);

  // FFN: gelu(S1 @ W1 + b1) -> H ; H @ W2 + b2 + S1 -> Y3 ; LN3 -> out
  gemm_nl<0,1,0,0><<<dim3(313, 16), 64, 0, stream>>>(S1, WF1, d_in[18], 0, nullptr, H,  MROWS, DFF, CC,  flag);
  gemm_nl<0,0,1,0><<<dim3(313, 4),  64, 0, stream>>>(H,  WF2, d_in[20], 0, S1,      Y3, MROWS, CC,  DFF, flag);
  ln_k<1><<<1250, 256, 0, stream>>>(Y3, d_in[21], d_in[22], d_out, MROWS, flag);
}

// Round 6
// 524.011 us; speedup vs baseline: 1.0764x; 1.0764x over previous
//
#include <hip/hip_runtime.h>

typedef unsigned short u16;
typedef __attribute__((ext_vector_type(8))) __bf16 bf8_t;
typedef __attribute__((ext_vector_type(4))) float f4_t;

union bf8u { u16 u[8]; bf8_t v; uint4 q; };

// ---------- bf16 helpers ----------
__device__ __forceinline__ float bf2f(u16 v) {
  return __uint_as_float(((unsigned int)v) << 16);
}
__device__ __forceinline__ u16 f2bf(float f) {
  unsigned int u = __float_as_uint(f);
  unsigned int r = u + 0x7FFFu + ((u >> 16) & 1u);  // RNE
  return (u16)(r >> 16);
}
__device__ __forceinline__ float bflo(unsigned int w) { return __uint_as_float(w << 16); }
__device__ __forceinline__ float bfhi(unsigned int w) { return __uint_as_float(w & 0xFFFF0000u); }
__device__ __forceinline__ float ldf1(const void* p, size_t i, int isf32) {
  return isf32 ? ((const float*)p)[i] : bf2f(((const u16*)p)[i]);
}

// ---------- sizes ----------
#define LQ    2500
#define LQP   2560      /* padded token count for Vt */
#define BB    2
#define CC    256
#define NCC   6
#define HFF   64
#define WFF   176
#define DFF   1024
#define MROWS 5000

// ---------- workspace byte offsets (end < 20.7MB proven-safe) ----------
#define WB_UV   256
#define WB_WQKV 240256
#define WB_WOP  633472
#define WB_WSC  764544
#define WB_WF1  895616
#define WB_WF2  1419904
#define WB_S1   1944192                 /* 2,621,440 each */
#define WB_S2   (WB_S1 + 2621440)
#define WB_S3   (WB_S2 + 2621440)
#define WB_VT   (WB_S3 + 2621440)       /* 512 x 2560 x 2B */
#define WB_H    WB_S2                   /* overlaps S2,S3,VT (dead at FFN time) */
#define WB_Y3   (WB_S2 + 10485760)

// ============================================================
__global__ void detect_k(const u16* __restrict__ rp, int* __restrict__ flag) {
  int bad = 0;
  for (int i = threadIdx.x; i < 7500; i += 64) {
    float v = bf2f(rp[i]);
    if (!(fabsf(v) < 1e6f)) bad = 1;
  }
  int anybad = __any(bad);
  if (threadIdx.x == 0) flag[0] = anybad ? 1 : 0;   // 1 = f32, 0 = bf16
}

// ============================================================
// weight prep: convert / transpose / zero-fill into bf16 ws
// ============================================================
struct WDesc {
  const void* src[6];
  u16* dst[6];
  int n[6];
  int mode[6];     // 0 direct, 1 transpose, 2 zero Vt pad
  int Kd[6], Nd[6];
};
__global__ __launch_bounds__(256) void cvtw_k(WDesc d, const int* __restrict__ flag) {
  const int df = flag[0];
  const int i = blockIdx.y;
  const int n = d.n[i];
  for (int j = blockIdx.x * 256 + threadIdx.x; j < n; j += gridDim.x * 256) {
    if (d.mode[i] == 2) {
      const int row = j / (LQP - LQ), col = LQ + j % (LQP - LQ);
      d.dst[i][(size_t)row * LQP + col] = 0;
    } else if (d.mode[i] == 1) {
      const int K = d.Kd[i], N = d.Nd[i];
      const int nn = j / K, kk = j - nn * K;
      d.dst[i][j] = f2bf(ldf1(d.src[i], (size_t)kk * N + nn, df));
    } else {
      d.dst[i][j] = f2bf(ldf1(d.src[i], j, df));
    }
  }
}

// ============================================================
// No-LDS MFMA GEMM, compile-time K: wave computes 16M x 64N.
// ============================================================
template<int KTPL, int XRAW, int ACT, int RES, int STORE_T>
__global__ __launch_bounds__(64) void gemm_nl(
    const void* __restrict__ Xv, const u16* __restrict__ W,
    const void* __restrict__ bias, size_t boff,
    const void* __restrict__ resv,
    u16* __restrict__ Y, int M, int N, const int* __restrict__ flag)
{
  const int df = flag[0];
  const int lane = threadIdx.x;
  const int ln15 = lane & 15, l4 = lane >> 4;
  const int m0 = blockIdx.x * 16, n0 = blockIdx.y * 64;
  const int am = min(m0 + ln15, M - 1);

  f4_t acc[4];
#pragma unroll
  for (int nt = 0; nt < 4; ++nt) acc[nt] = (f4_t){0.f, 0.f, 0.f, 0.f};

#pragma unroll 8
  for (int k0 = 0; k0 < KTPL; k0 += 32) {
    bf8u a;
    if (XRAW && df) {
      const float* p = (const float*)Xv + (size_t)am * KTPL + k0 + l4 * 8;
      float4 r0 = *(const float4*)p, r1 = *(const float4*)(p + 4);
      a.u[0]=f2bf(r0.x); a.u[1]=f2bf(r0.y); a.u[2]=f2bf(r0.z); a.u[3]=f2bf(r0.w);
      a.u[4]=f2bf(r1.x); a.u[5]=f2bf(r1.y); a.u[6]=f2bf(r1.z); a.u[7]=f2bf(r1.w);
    } else {
      a.q = *(const uint4*)((const u16*)Xv + (size_t)am * KTPL + k0 + l4 * 8);
    }
#pragma unroll
    for (int nt = 0; nt < 4; ++nt) {
      bf8u b;
      b.q = *(const uint4*)&W[(size_t)(n0 + nt * 16 + ln15) * KTPL + k0 + l4 * 8];
      acc[nt] = __builtin_amdgcn_mfma_f32_16x16x32_bf16(a.v, b.v, acc[nt], 0, 0, 0);
    }
  }
#pragma unroll
  for (int nt = 0; nt < 4; ++nt) {
    const int gn = n0 + nt * 16 + ln15;
    const float bv = ldf1(bias, boff + gn, df);
#pragma unroll
    for (int r = 0; r < 4; ++r) {
      const int gm = m0 + l4 * 4 + r;
      if (gm < M) {
        float x = acc[nt][r] + bv;
        if (ACT) x = 0.5f * x * (1.f + erff(x * 0.70710678118654752f));
        if (RES == 1)      x += bf2f(((const u16*)resv)[(size_t)gm * N + gn]);
        else if (RES == 2) x += ldf1(resv, (size_t)gm * N + gn, df);
        if (STORE_T) Y[(size_t)(gn + (gm & 1) * 256) * LQP + (gm >> 1)] = f2bf(x);
        else         Y[(size_t)gm * N + gn] = f2bf(x);
      }
    }
  }
}

// ============================================================
// Split-K flash attention: block = 4 waves sharing one 16-q strip,
// wave w handles k-tiles [w*10, w*10+10). LDS merge of partials.
// ============================================================
#define TPW 10
__global__ __launch_bounds__(256) void attn_mf(
    const u16* __restrict__ Qw, const u16* __restrict__ Kw,
    const u16* __restrict__ Vt, u16* __restrict__ Ow)
{
  __shared__ __align__(16) u16 sP[4][16 * 72];
  __shared__ float sO[4][16][32];
  __shared__ float sM[4][16];
  __shared__ float sL[4][16];
  const int t = threadIdx.x;
  const int lane = t & 63, w = t >> 6;
  const int ln15 = lane & 15, l4 = lane >> 4;
  const int q0 = blockIdx.x * 16;
  const int by = blockIdx.y;           // b*8+h
  const int b = by >> 3, h = by & 7;
  u16* myP = &sP[w][0];
  const float SCL2E = 0.25505654481f;  // (1/sqrt(32)) * log2(e)

  bf8u aq;
  {
    const int qrow = min(q0 + ln15, LQ - 1);
    bf8u qr; qr.q = *(const uint4*)&Qw[((size_t)qrow * BB + b) * CC + h * 32 + l4 * 8];
#pragma unroll
    for (int i = 0; i < 8; ++i) aq.u[i] = f2bf(bf2f(qr.u[i]) * SCL2E);
  }

  f4_t oacc[2];
  oacc[0] = (f4_t){0.f,0.f,0.f,0.f};
  oacc[1] = (f4_t){0.f,0.f,0.f,0.f};
  float m_r[4] = {-1e30f, -1e30f, -1e30f, -1e30f};
  float l_r[4] = {0.f, 0.f, 0.f, 0.f};

  for (int kt = w * TPW; kt < w * TPW + TPW; ++kt) {
    const int kb = kt * 64;
    f4_t sv[4];
#pragma unroll
    for (int nt = 0; nt < 4; ++nt) {
      bf8u bk;
      bk.q = *(const uint4*)&Kw[((size_t)(kb + nt * 16 + ln15) * BB + b) * CC + h * 32 + l4 * 8];
      f4_t z = (f4_t){0.f,0.f,0.f,0.f};
      sv[nt] = __builtin_amdgcn_mfma_f32_16x16x32_bf16(aq.v, bk.v, z, 0, 0, 0);
    }
    float p[4][4];
    if (kb + 64 <= LQ) {
#pragma unroll
      for (int nt = 0; nt < 4; ++nt)
#pragma unroll
        for (int r = 0; r < 4; ++r) p[nt][r] = sv[nt][r];
    } else {
#pragma unroll
      for (int nt = 0; nt < 4; ++nt) {
        const bool ok = (kb + nt * 16 + ln15) < LQ;
#pragma unroll
        for (int r = 0; r < 4; ++r) p[nt][r] = ok ? sv[nt][r] : -1e30f;
      }
    }
#pragma unroll
    for (int r = 0; r < 4; ++r) {
      float mloc = fmaxf(fmaxf(p[0][r], p[1][r]), fmaxf(p[2][r], p[3][r]));
      mloc = fmaxf(mloc, __shfl_xor(mloc, 1));
      mloc = fmaxf(mloc, __shfl_xor(mloc, 2));
      mloc = fmaxf(mloc, __shfl_xor(mloc, 4));
      mloc = fmaxf(mloc, __shfl_xor(mloc, 8));
      const float mn = fmaxf(m_r[r], mloc);
      const float alpha = __builtin_amdgcn_exp2f(m_r[r] - mn);
      m_r[r] = mn;
      float s = 0.f;
#pragma unroll
      for (int nt = 0; nt < 4; ++nt) {
        const float e = __builtin_amdgcn_exp2f(p[nt][r] - mn);
        p[nt][r] = e; s += e;
      }
      s += __shfl_xor(s, 1);
      s += __shfl_xor(s, 2);
      s += __shfl_xor(s, 4);
      s += __shfl_xor(s, 8);
      l_r[r] = l_r[r] * alpha + s;
      oacc[0][r] *= alpha;
      oacc[1][r] *= alpha;
    }
#pragma unroll
    for (int nt = 0; nt < 4; ++nt)
#pragma unroll
      for (int r = 0; r < 4; ++r)
        myP[(l4 * 4 + r) * 72 + nt * 16 + ln15] = f2bf(p[nt][r]);
#pragma unroll
    for (int ks = 0; ks < 2; ++ks) {
      bf8u ap;
      ap.q = *(const uint4*)&myP[ln15 * 72 + ks * 32 + l4 * 8];
#pragma unroll
      for (int nt = 0; nt < 2; ++nt) {
        bf8u bv;
        bv.q = *(const uint4*)&Vt[(size_t)(by * 32 + nt * 16 + ln15) * LQP + kb + ks * 32 + l4 * 8];
        oacc[nt] = __builtin_amdgcn_mfma_f32_16x16x32_bf16(ap.v, bv.v, oacc[nt], 0, 0, 0);
      }
    }
  }
  // ---- write partials, merge in LDS ----
#pragma unroll
  for (int nt = 0; nt < 2; ++nt)
#pragma unroll
    for (int r = 0; r < 4; ++r)
      sO[w][l4 * 4 + r][nt * 16 + ln15] = oacc[nt][r];
  if (ln15 == 0) {
#pragma unroll
    for (int r = 0; r < 4; ++r) { sM[w][l4 * 4 + r] = m_r[r]; sL[w][l4 * 4 + r] = l_r[r]; }
  }
  __syncthreads();
#pragma unroll
  for (int i = t; i < 512; i += 256) {
    const int row = i >> 5, col = i & 31;
    const float M = fmaxf(fmaxf(sM[0][row], sM[1][row]), fmaxf(sM[2][row], sM[3][row]));
    float l = 0.f, O = 0.f;
#pragma unroll
    for (int w4 = 0; w4 < 4; ++w4) {
      const float sc = __builtin_amdgcn_exp2f(sM[w4][row] - M);
      l += sc * sL[w4][row];
      O += sc * sO[w4][row][col];
    }
    const int q = q0 + row;
    if (q < LQ)
      Ow[((size_t)q * BB + b) * CC + h * 32 + col] = f2bf(O / l);
  }
}

// ============================================================
// LayerNorm over C=256; one wave per row; 4 rows per block.
// ============================================================
template<int TOOUT>
__global__ __launch_bounds__(256) void ln_k(const u16* __restrict__ X,
    const void* __restrict__ g, const void* __restrict__ be,
    void* __restrict__ Yv, int rows, const int* __restrict__ flag)
{
  const int df = flag[0];
  const int lane = threadIdx.x & 63;
  const int row = blockIdx.x * 4 + (threadIdx.x >> 6);
  if (row >= rows) return;
  uint2 raw = *(const uint2*)(X + (size_t)row * CC + lane * 4);
  float vx = bflo(raw.x), vy = bfhi(raw.x), vz = bflo(raw.y), vw = bfhi(raw.y);
  float s = vx + vy + vz + vw;
#pragma unroll
  for (int o = 1; o < 64; o <<= 1) s += __shfl_xor(s, o);
  const float mean = s * 0.00390625f;
  const float dx = vx - mean, dy = vy - mean, dz = vz - mean, dw = vw - mean;
  float sq = dx*dx + dy*dy + dz*dz + dw*dw;
#pragma unroll
  for (int o = 1; o < 64; o <<= 1) sq += __shfl_xor(sq, o);
  const float rstd = rsqrtf(sq * 0.00390625f + 1e-5f);
  const float g0 = ldf1(g, lane*4+0, df), g1 = ldf1(g, lane*4+1, df);
  const float g2 = ldf1(g, lane*4+2, df), g3 = ldf1(g, lane*4+3, df);
  const float b0 = ldf1(be, lane*4+0, df), b1 = ldf1(be, lane*4+1, df);
  const float b2 = ldf1(be, lane*4+2, df), b3 = ldf1(be, lane*4+3, df);
  const float y0 = dx * rstd * g0 + b0;
  const float y1 = dy * rstd * g1 + b1;
  const float y2 = dz * rstd * g2 + b2;
  const float y3 = dw * rstd * g3 + b3;
  if (TOOUT && df) {
    float* yp = (float*)Yv + (size_t)row * CC + lane * 4;
    *(float4*)yp = make_float4(y0, y1, y2, y3);
  } else {
    u16* yp = (u16*)Yv + (size_t)row * CC + lane * 4;
    unsigned int lo = (unsigned int)f2bf(y0) | ((unsigned int)f2bf(y1) << 16);
    unsigned int hi = (unsigned int)f2bf(y2) | ((unsigned int)f2bf(y3) << 16);
    *(uint2*)yp = make_uint2(lo, hi);
  }
}

// ============================================================
__global__ __launch_bounds__(256) void uv_k(
    const void* __restrict__ refp, const void* __restrict__ intr,
    const void* __restrict__ extr, float* __restrict__ uv,
    const int* __restrict__ flag)
{
  const int df = flag[0];
  const int idx = blockIdx.x * 256 + threadIdx.x;
  if (idx >= BB * NCC * LQ) return;
  const int bc = idx / LQ;
  const int q = idx - bc * LQ;
  float R[3][3], tv[3], Kc[3][3], p[3];
#pragma unroll
  for (int i = 0; i < 3; ++i) {
#pragma unroll
    for (int j = 0; j < 3; ++j) {
      R[i][j] = ldf1(extr, bc*16 + i*4 + j, df);
      Kc[i][j] = ldf1(intr, bc*9 + i*3 + j, df);
    }
    tv[i] = ldf1(extr, bc*16 + i*4 + 3, df);
  }
#pragma unroll
  for (int j = 0; j < 3; ++j) p[j] = ldf1(refp, q*3 + j, df) - tv[j];
  float pc[3];
#pragma unroll
  for (int i = 0; i < 3; ++i) pc[i] = R[0][i]*p[0] + R[1][i]*p[1] + R[2][i]*p[2];
  float im[3];
#pragma unroll
  for (int i = 0; i < 3; ++i) im[i] = Kc[i][0]*pc[0] + Kc[i][1]*pc[1] + Kc[i][2]*pc[2];
  const float z = fmaxf(im[2], 1e-5f);
  uv[(size_t)idx*2 + 0] = im[0] / z - 0.5f;
  uv[(size_t)idx*2 + 1] = im[1] / z - 0.5f;
}

// ============================================================
__global__ __launch_bounds__(256) void samp_k(
    const void* __restrict__ feat, const float* __restrict__ uv,
    u16* __restrict__ S, const int* __restrict__ flag)
{
  const int df = flag[0];
  const int c = blockIdx.x;
  const int b = blockIdx.y / 5;
  const int ch = blockIdx.y % 5;
  const int qend = min((ch + 1) * 500, LQ);
  for (int q = ch * 500 + threadIdx.x; q < qend; q += 256) {
    float acc = 0.f;
#pragma unroll
    for (int cam = 0; cam < NCC; ++cam) {
      const int bc = b * NCC + cam;
      const float x = uv[((size_t)bc * LQ + q) * 2 + 0];
      const float y = uv[((size_t)bc * LQ + q) * 2 + 1];
      const float xf = floorf(x), yf = floorf(y);
      const int x0 = (int)xf, y0 = (int)yf;
      const float wx = x - xf, wy = y - yf;
      const size_t base = ((size_t)bc * CC + c) * (HFF * WFF);
      const bool vx0 = (x0 >= 0) & (x0 < WFF);
      const bool vx1 = (x0 + 1 >= 0) & (x0 + 1 < WFF);
      const bool vy0 = (y0 >= 0) & (y0 < HFF);
      const bool vy1 = (y0 + 1 >= 0) & (y0 + 1 < HFF);
      if (vy0) {
        const size_t rb = base + (size_t)y0 * WFF;
        if (vx0) acc += (1.f - wx) * (1.f - wy) * ldf1(feat, rb + x0, df);
        if (vx1) acc += wx * (1.f - wy) * ldf1(feat, rb + x0 + 1, df);
      }
      if (vy1) {
        const size_t rb = base + (size_t)(y0 + 1) * WFF;
        if (vx0) acc += (1.f - wx) * wy * ldf1(feat, rb + x0, df);
        if (vx1) acc += wx * wy * ldf1(feat, rb + x0 + 1, df);
      }
    }
    S[((size_t)q * BB + b) * CC + c] = f2bf(acc * (1.f / 6.f));
  }
}

// ============================================================
extern "C" void kernel_launch(void* const* d_in, const int* in_sizes, int n_in,
                              void* d_out, int out_size, void* d_ws, size_t ws_size,
                              hipStream_t stream) {
  (void)in_sizes; (void)n_in; (void)out_size; (void)ws_size;
  char* base = (char*)d_ws;
  int* flag = (int*)base;
  float* UV = (float*)(base + WB_UV);
  u16* WQKV = (u16*)(base + WB_WQKV);
  u16* WOP  = (u16*)(base + WB_WOP);
  u16* WSC  = (u16*)(base + WB_WSC);
  u16* WF1  = (u16*)(base + WB_WF1);
  u16* WF2  = (u16*)(base + WB_WF2);
  u16* S1 = (u16*)(base + WB_S1);
  u16* S2 = (u16*)(base + WB_S2);
  u16* S3 = (u16*)(base + WB_S3);
  u16* VT = (u16*)(base + WB_VT);
  u16* H  = (u16*)(base + WB_H);
  u16* Y3 = (u16*)(base + WB_Y3);

  detect_k<<<1, 64, 0, stream>>>((const u16*)d_in[3], flag);

  WDesc wd;
  wd.src[0] = d_in[7];  wd.dst[0] = WQKV; wd.n[0] = 196608; wd.mode[0] = 0; wd.Kd[0] = 0;    wd.Nd[0] = 0;
  wd.src[1] = d_in[9];  wd.dst[1] = WOP;  wd.n[1] = 65536;  wd.mode[1] = 0; wd.Kd[1] = 0;    wd.Nd[1] = 0;
  wd.src[2] = d_in[13]; wd.dst[2] = WSC;  wd.n[2] = 65536;  wd.mode[2] = 0; wd.Kd[2] = 0;    wd.Nd[2] = 0;
  wd.src[3] = d_in[17]; wd.dst[3] = WF1;  wd.n[3] = 262144; wd.mode[3] = 1; wd.Kd[3] = 256;  wd.Nd[3] = 1024;
  wd.src[4] = d_in[19]; wd.dst[4] = WF2;  wd.n[4] = 262144; wd.mode[4] = 1; wd.Kd[4] = 1024; wd.Nd[4] = 256;
  wd.src[5] = nullptr;  wd.dst[5] = VT;   wd.n[5] = 512 * (LQP - LQ); wd.mode[5] = 2; wd.Kd[5] = 0; wd.Nd[5] = 0;
  cvtw_k<<<dim3(128, 6), 256, 0, stream>>>(wd, flag);

  uv_k<<<(BB * NCC * LQ + 255) / 256, 256, 0, stream>>>(d_in[3], d_in[4], d_in[5], UV, flag);

  // QKV projections: Q->S1, K->S2, V->VT (transposed store)
  gemm_nl<256,1,0,0,0><<<dim3(313, 4), 64, 0, stream>>>(d_in[0], WQKV,          d_in[8], 0,   nullptr, S1, MROWS, CC, flag);
  gemm_nl<256,1,0,0,0><<<dim3(313, 4), 64, 0, stream>>>(d_in[1], WQKV + 65536,  d_in[8], 256, nullptr, S2, MROWS, CC, flag);
  gemm_nl<256,1,0,0,1><<<dim3(313, 4), 64, 0, stream>>>(d_in[1], WQKV + 131072, d_in[8], 512, nullptr, VT, MROWS, CC, flag);

  attn_mf<<<dim3(157, 16), 256, 0, stream>>>(S1, S2, VT, S3);

  // out-proj (+bevq residual) -> S1, LN1 -> S2
  gemm_nl<256,0,0,2,0><<<dim3(313, 4), 64, 0, stream>>>(S3, WOP, d_in[10], 0, d_in[0], S1, MROWS, CC, flag);
  ln_k<0><<<1250, 256, 0, stream>>>(S1, d_in[11], d_in[12], S2, MROWS, flag);

  // sampling -> VT slot (dead after attn)
  samp_k<<<dim3(CC, BB * 5), 256, 0, stream>>>(d_in[2], UV, VT, flag);

  // SCA (+S2 residual) -> S3, LN2 -> S1
  gemm_nl<256,0,0,1,0><<<dim3(313, 4), 64, 0, stream>>>(VT, WSC, d_in[14], 0, S2, S3, MROWS, CC, flag);
  ln_k<0><<<1250, 256, 0, stream>>>(S3, d_in[15], d_in[16], S1, MROWS, flag);

  // FFN: gelu(S1 @ W1 + b1) -> H ; H @ W2 + b2 + S1 -> Y3 ; LN3 -> out
  gemm_nl<256,0,1,0,0><<<dim3(313, 16), 64, 0, stream>>>(S1, WF1, d_in[18], 0, nullptr, H,  MROWS, DFF, flag);
  gemm_nl<1024,0,0,1,0><<<dim3(313, 4),  64, 0, stream>>>(H,  WF2, d_in[20], 0, S1,      Y3, MROWS, CC,  flag);
  ln_k<1><<<1250, 256, 0, stream>>>(Y3, d_in[21], d_in[22], d_out, MROWS, flag);
}